// Round 10
// baseline (112.284 us; speedup 1.0000x reference)
//
#include <hip/hip_runtime.h>
#include <math.h>
#include <stdint.h>

#define NN 7
#define HD 128
#define FIN 32
#define TPB 8            // 8 tokens per block; 4 waves, each owns 2 tokens
#define LN_EPS 1e-5f
#define ALPHA 0.2f
#define NEG_CONST -9e15f
#define SCALE 0.08838834764831845f  // 128^-0.5

typedef __bf16 bf16x8 __attribute__((ext_vector_type(8)));
typedef float  f32x4  __attribute__((ext_vector_type(4)));

// intra-wave LDS ordering; sched_barrier stops hoisting past the wait (rule #18)
#define FENCE() do { asm volatile("s_waitcnt lgkmcnt(0)" ::: "memory"); \
                     __builtin_amdgcn_sched_barrier(0); } while (0)

__device__ __forceinline__ uint16_t f2bf_u(float f) {
    union { float f; uint32_t u; } v; v.f = f;
    uint32_t r = v.u + 0x7FFFu + ((v.u >> 16) & 1u);  // RNE
    return (uint16_t)(r >> 16);
}
__device__ __forceinline__ uint32_t pack2(float a, float b) {
    return (uint32_t)f2bf_u(a) | ((uint32_t)f2bf_u(b) << 16);
}

// DPP lane-reduce: ctrl must be an ICE -> template parameter
template <int CTRL>
__device__ __forceinline__ float dpp_add(float v) {
    union { float f; int i; } a, r;
    a.f = v;
    r.i = __builtin_amdgcn_update_dpp(a.i, a.i, CTRL, 0xF, 0xF, false);
    return v + r.f;
}
__device__ __forceinline__ float sum16(float v) {
    v = dpp_add<0xB1>(v);    // quad_perm [1,0,3,2] : xor 1
    v = dpp_add<0x4E>(v);    // quad_perm [2,3,0,1] : xor 2
    v = dpp_add<0x124>(v);   // row_ror:4
    v = dpp_add<0x128>(v);   // row_ror:8
    return v;
}

// ws layout (bytes):
//  WpTp[896][32] bf16 @0 | W1Tp[128][128] bf16 @57344 | W2Tp[128][128] bf16 @90112
//  | vabp[2][2][128] f32 @122880 | bpp[896] f32 @124928 | gbp[2][2][128] f32 @128512
#define WS_W1T  57344
#define WS_W2T  90112
#define WS_VAB  122880
#define WS_BPP  124928
#define WS_GBP  128512

__global__ __launch_bounds__(256) void prep_weights(
    const float* __restrict__ Wp, const float* __restrict__ bp,
    const float* __restrict__ W1, const float* __restrict__ a1,
    const float* __restrict__ g1, const float* __restrict__ b1,
    const float* __restrict__ W2, const float* __restrict__ a2,
    const float* __restrict__ g2, const float* __restrict__ b2,
    uint16_t* __restrict__ WpT, uint16_t* __restrict__ W1T,
    uint16_t* __restrict__ W2T, float* __restrict__ vab,
    float* __restrict__ bpp, float* __restrict__ gbp)
{
    const int bid = blockIdx.x, tid = threadIdx.x;
    if (bid < 112) {                 // WpTp[sig(gc)][f] = Wp[f][gc]
        int idx = bid * 256 + tid;
        int gc = idx >> 5, f = idx & 31;
        int gcp = (gc & ~127) | (((gc & 15) << 3) | ((gc & 127) >> 4));
        WpT[gcp * 32 + f] = f2bf_u(Wp[(size_t)f * (NN * HD) + gc]);
    } else if (bid < 176) {          // W1Tp[c][sig(k)] = W1[k][c]
        int idx = (bid - 112) * 256 + tid;
        int c = idx >> 7, k = idx & 127;
        int kp = ((k & 15) << 3) | (k >> 4);
        W1T[c * 128 + kp] = f2bf_u(W1[(size_t)k * HD + c]);
    } else if (bid < 240) {          // W2Tp[c][sig(k)] = W2[k][c]
        int idx = (bid - 176) * 256 + tid;
        int c = idx >> 7, k = idx & 127;
        int kp = ((k & 15) << 3) | (k >> 4);
        W2T[c * 128 + kp] = f2bf_u(W2[(size_t)k * HD + c]);
    } else {
        // vabp[l][which][sig(j)] = sum_o W[j][o]*a[which*128+o]
        for (int d = tid; d < 512; d += 256) {
            int l = d >> 8, which = (d >> 7) & 1, j = d & 127;
            const float* W = l ? W2 : W1;
            const float* a = (l ? a2 : a1) + which * HD;
            const float* row = W + (size_t)j * HD;
            float acc = 0.f;
            #pragma unroll 8
            for (int o = 0; o < HD; o += 4) {
                f32x4 wv = *reinterpret_cast<const f32x4*>(&row[o]);
                acc += wv[0]*a[o] + wv[1]*a[o+1] + wv[2]*a[o+2] + wv[3]*a[o+3];
            }
            int jp = ((j & 15) << 3) | (j >> 4);
            vab[l * 256 + which * 128 + jp] = acc;
        }
        // bpp[sig_g(gc)] = bp[gc]
        for (int gc = tid; gc < NN * HD; gc += 256) {
            int gcp = (gc & ~127) | (((gc & 15) << 3) | ((gc & 127) >> 4));
            bpp[gcp] = bp[gc];
        }
        // gbp[l][{g,b}][sig(c)]
        for (int e = tid; e < 512; e += 256) {
            int l = e >> 8, which = (e >> 7) & 1, c = e & 127;
            const float* src = l ? (which ? b2 : g2) : (which ? b1 : g1);
            int cp = ((c & 15) << 3) | (c >> 4);
            gbp[l * 256 + which * 128 + cp] = src[c];
        }
    }
}

__global__ __launch_bounds__(256, 5) void gat_fused(
    const float* __restrict__ x, const float* __restrict__ adj,
    const float* __restrict__ bpp,
    const uint16_t* __restrict__ WpT, const uint16_t* __restrict__ W1T,
    const uint16_t* __restrict__ W2T, const float* __restrict__ vab,
    const float* __restrict__ gbp,
    float* __restrict__ out, int BT)
{
    // fp32 residual h, sigma-permuted columns; per-wave slices, 14 rows each.
    // 132-col pad: row stride 528 B -> rows offset by 4 banks, 16B-aligned.
    __shared__ __align__(16) float h_s[4][14][132];   // 29568 B -> 5 blocks/CU

    const int tid  = threadIdx.x;
    const int lane = tid & 63;
    const int wave = tid >> 6;
    const int frow = lane & 15;
    const int kgrp = lane >> 4;
    const int kb   = kgrp * 8;
    const int t0   = blockIdx.x * TPB;

    // per-lane attention-row identity (frow 14,15 -> harmless dup of row 13)
    const int tt = (frow >= NN) ? 1 : 0;
    int np = frow - tt * NN; if (np > 6) np = 6;

    uint32_t amask = 0;
    #pragma unroll
    for (int j = 0; j < NN; ++j)
        amask |= (adj[np * NN + j] > 0.f) ? (1u << j) : 0u;

    // ---- B-frag: x for the block's 8 tokens (B col = token) ----
    bf16x8 bx;
    {
        union { bf16x8 v; uint32_t u[4]; } bu;
        bu.u[0] = bu.u[1] = bu.u[2] = bu.u[3] = 0;
        int tok = t0 + frow;
        if (frow < TPB && tok < BT) {
            f32x4 xa = *reinterpret_cast<const f32x4*>(&x[(size_t)tok * FIN + kb]);
            f32x4 xb = *reinterpret_cast<const f32x4*>(&x[(size_t)tok * FIN + kb + 4]);
            bu.u[0] = pack2(xa[0], xa[1]);
            bu.u[1] = pack2(xa[2], xa[3]);
            bu.u[2] = pack2(xb[0], xb[1]);
            bu.u[3] = pack2(xb[2], xb[3]);
        }
        bx = bu.v;
    }

    // ---- cooperative projection (WpT rows pre-sorted in sigma space) ----
    #pragma unroll 2
    for (int i = 0; i < 14; ++i) {
        int tile = wave * 14 + i;
        bf16x8 av = *reinterpret_cast<const bf16x8*>(WpT + (size_t)(tile * 16 + frow) * FIN + kb);
        f32x4 acc = {0.f, 0.f, 0.f, 0.f};
        acc = __builtin_amdgcn_mfma_f32_16x16x32_bf16(av, bx, acc, 0, 0, 0);
        int tok = t0 + frow;                 // C col = token, C row = out-col'
        if (frow < TPB && tok < BT) {
            int gc0 = tile * 16 + kgrp * 4;  // 4 consecutive sigma-cols, same node
            f32x4 bias = *reinterpret_cast<const f32x4*>(&bpp[gc0]);
            f32x4 v = {acc[0]+bias[0], acc[1]+bias[1], acc[2]+bias[2], acc[3]+bias[3]};
            int n = gc0 >> 7, kk = gc0 & 127;
            *reinterpret_cast<f32x4*>(&h_s[frow >> 1][(frow & 1) * NN + n][kk]) = v;
        }
    }
    __syncthreads();   // the only block barrier

    for (int l = 0; l < 2; ++l) {
        const uint16_t* __restrict__ WT  = l ? W2T : W1T;
        const float*    __restrict__ vv0 = vab + l * 256;
        const float*    __restrict__ ggp = gbp + l * 256;  // [0..127]=gamma', [128..255]=beta'

        // ---- phase A: f-dots (slot = lane>>1; 0-13 f_src rows, 16-29 f_dst rows) ----
        float facc = 0.f;
        {
            int slot = lane >> 1, half = lane & 1;
            int which = (slot >> 4) & 1;
            int row = slot & 15; if (row > 13) row = 13;
            const float* hr = &h_s[wave][row][half * 64];
            const f32x4* vp = reinterpret_cast<const f32x4*>(vv0 + which * HD + half * 64);
            #pragma unroll
            for (int i2 = 0; i2 < 16; ++i2) {
                f32x4 hv = *reinterpret_cast<const f32x4*>(hr + i2 * 4);
                f32x4 w  = vp[i2];
                facc += hv[0]*w[0] + hv[1]*w[1] + hv[2]*w[2] + hv[3]*w[3];
            }
            facc = dpp_add<0xB1>(facc);   // combine half-pairs (xor 1, VALU pipe)
        }

        // ---- phase B: per-lane softmax for row (tt,np); shfl full-EXEC ----
        float p[NN];
        {
            float fs = __shfl(facc, 2 * (tt * NN + np), 64);
            float e[NN]; float mx = -INFINITY;
            #pragma unroll
            for (int j = 0; j < NN; ++j) {
                float fd = __shfl(facc, 32 + 2 * (tt * NN + j), 64);
                float v = fs + fd;
                v = (v > 0.f ? v : ALPHA * v) * SCALE;
                v = ((amask >> j) & 1u) ? v : NEG_CONST;
                e[j] = v; mx = fmaxf(mx, v);
            }
            float ssum = 0.f;
            #pragma unroll
            for (int j = 0; j < NN; ++j) { e[j] = __expf(e[j] - mx); ssum += e[j]; }
            float inv = 1.f / ssum;
            #pragma unroll
            for (int j = 0; j < NN; ++j) p[j] = e[j] * inv;
        }

        // ---- phase C: A-frag build g[frow][sig-cols] = sum_j p[j]*h[tt*7+j][..] ----
        //      fp32 reads, no unpack; bf16 conversion only at the final frag pack.
        bf16x8 av4[4];
        #pragma unroll
        for (int ks = 0; ks < 4; ++ks) {
            f32x4 ga0 = {0.f,0.f,0.f,0.f}, ga1 = {0.f,0.f,0.f,0.f};
            #pragma unroll
            for (int j = 0; j < NN; ++j) {
                const float* hj = &h_s[wave][tt * NN + j][ks * 32 + kb];
                f32x4 h0 = *reinterpret_cast<const f32x4*>(hj);
                f32x4 h1 = *reinterpret_cast<const f32x4*>(hj + 4);
                float pj = p[j];
                ga0[0] += pj*h0[0]; ga0[1] += pj*h0[1]; ga0[2] += pj*h0[2]; ga0[3] += pj*h0[3];
                ga1[0] += pj*h1[0]; ga1[1] += pj*h1[1]; ga1[2] += pj*h1[2]; ga1[3] += pj*h1[3];
            }
            union { bf16x8 v; uint32_t u[4]; } bu;
            bu.u[0] = pack2(ga0[0], ga0[1]); bu.u[1] = pack2(ga0[2], ga0[3]);
            bu.u[2] = pack2(ga1[0], ga1[1]); bu.u[3] = pack2(ga1[2], ga1[3]);
            av4[ks] = bu.v;
        }

        // ---- phase D: GEMM hp = g @ W  (k-space sigma-permuted on both sides) ----
        f32x4 Cacc[8];
        #pragma unroll
        for (int ntl = 0; ntl < 8; ++ntl) {
            const uint16_t* bpg = WT + (size_t)(ntl * 16 + frow) * HD + kb;
            f32x4 acc = {0.f, 0.f, 0.f, 0.f};
            #pragma unroll
            for (int ks = 0; ks < 4; ++ks) {
                bf16x8 bv = *reinterpret_cast<const bf16x8*>(bpg + ks * 32);
                acc = __builtin_amdgcn_mfma_f32_16x16x32_bf16(av4[ks], bv, acc, 0, 0, 0);
            }
            Cacc[ntl] = acc;
        }

        // ---- phase E: LayerNorm + residual; fp32 b128 RMW, no bf16 round-trip ----
        {
            f32x4 gv0 = *reinterpret_cast<const f32x4*>(ggp + frow * 8);
            f32x4 gv1 = *reinterpret_cast<const f32x4*>(ggp + frow * 8 + 4);
            f32x4 bv0 = *reinterpret_cast<const f32x4*>(ggp + 128 + frow * 8);
            f32x4 bv1 = *reinterpret_cast<const f32x4*>(ggp + 128 + frow * 8 + 4);
            #pragma unroll
            for (int r = 0; r < 4; ++r) {
                float s = 0.f, sq = 0.f;
                #pragma unroll
                for (int q = 0; q < 8; ++q) { float c = Cacc[q][r]; s += c; sq += c * c; }
                s = sum16(s); sq = sum16(sq);   // DPP all-reduce over 16 frow-lanes
                float mean = s * (1.f / HD);
                float var  = sq * (1.f / HD) - mean * mean;
                float rinv = rsqrtf(var + LN_EPS);
                int m = kgrp * 4 + r;
                if (m < 14) {
                    float* hp = &h_s[wave][m][frow * 8];
                    f32x4 h0 = *reinterpret_cast<const f32x4*>(hp);
                    f32x4 h1 = *reinterpret_cast<const f32x4*>(hp + 4);
                    h0[0] += (Cacc[0][r]-mean)*rinv*gv0[0] + bv0[0];
                    h0[1] += (Cacc[1][r]-mean)*rinv*gv0[1] + bv0[1];
                    h0[2] += (Cacc[2][r]-mean)*rinv*gv0[2] + bv0[2];
                    h0[3] += (Cacc[3][r]-mean)*rinv*gv0[3] + bv0[3];
                    h1[0] += (Cacc[4][r]-mean)*rinv*gv1[0] + bv1[0];
                    h1[1] += (Cacc[5][r]-mean)*rinv*gv1[1] + bv1[1];
                    h1[2] += (Cacc[6][r]-mean)*rinv*gv1[2] + bv1[2];
                    h1[3] += (Cacc[7][r]-mean)*rinv*gv1[3] + bv1[3];
                    *reinterpret_cast<f32x4*>(hp)     = h0;
                    *reinterpret_cast<f32x4*>(hp + 4) = h1;
                }
            }
        }
        FENCE();
    }

    // ---- out = mean over nodes; de-permute sigma columns on store ----
    {
        int t = lane >> 5, cq = lane & 31;
        int tok = t0 + wave * 2 + t;
        if (tok < BT) {
            int cp0 = cq * 4;                       // 4 consecutive sigma-cols
            f32x4 s = {0.f, 0.f, 0.f, 0.f};
            #pragma unroll
            for (int n = 0; n < NN; ++n) {
                f32x4 hv = *reinterpret_cast<const f32x4*>(&h_s[wave][t * NN + n][cp0]);
                s[0] += hv[0]; s[1] += hv[1]; s[2] += hv[2]; s[3] += hv[3];
            }
            const float inv7 = 1.f / 7.f;
            float* ob = out + (size_t)tok * HD;
            // inverse: c = (cp&7)*16 + (cp>>3)
            ob[((cp0    ) & 7) * 16 + ((cp0    ) >> 3)] = s[0] * inv7;
            ob[((cp0 + 1) & 7) * 16 + ((cp0 + 1) >> 3)] = s[1] * inv7;
            ob[((cp0 + 2) & 7) * 16 + ((cp0 + 2) >> 3)] = s[2] * inv7;
            ob[((cp0 + 3) & 7) * 16 + ((cp0 + 3) >> 3)] = s[3] * inv7;
        }
    }
}

extern "C" void kernel_launch(void* const* d_in, const int* in_sizes, int n_in,
                              void* d_out, int out_size, void* d_ws, size_t ws_size,
                              hipStream_t stream) {
    const float* x   = (const float*)d_in[0];
    const float* adj = (const float*)d_in[1];
    const float* Wp  = (const float*)d_in[2];
    const float* bp  = (const float*)d_in[3];
    const float* W1  = (const float*)d_in[4];
    const float* a1  = (const float*)d_in[5];
    const float* g1  = (const float*)d_in[6];
    const float* b1  = (const float*)d_in[7];
    const float* W2  = (const float*)d_in[8];
    const float* a2  = (const float*)d_in[9];
    const float* g2  = (const float*)d_in[10];
    const float* b2  = (const float*)d_in[11];
    const int BT = in_sizes[0] / FIN;
    const int blocks = (BT + TPB - 1) / TPB;

    uint8_t* ws = (uint8_t*)d_ws;
    uint16_t* WpT = (uint16_t*)(ws);
    uint16_t* W1T = (uint16_t*)(ws + WS_W1T);
    uint16_t* W2T = (uint16_t*)(ws + WS_W2T);
    float*    vab = (float*)   (ws + WS_VAB);
    float*    bpp = (float*)   (ws + WS_BPP);
    float*    gbp = (float*)   (ws + WS_GBP);

    prep_weights<<<dim3(241), dim3(256), 0, stream>>>(
        Wp, bp, W1, a1, g1, b1, W2, a2, g2, b2, WpT, W1T, W2T, vab, bpp, gbp);
    gat_fused<<<dim3(blocks), dim3(256), 0, stream>>>(
        x, adj, bpp, WpT, W1T, W2T, vab, gbp, (float*)d_out, BT);
}

// Round 11
// 77.104 us; speedup vs baseline: 1.4563x; 1.4563x over previous
//
#include <hip/hip_runtime.h>
#include <math.h>
#include <stdint.h>

#define NN 7
#define HD 128
#define FIN 32
#define TPB 16           // 16 tokens per block; 4 waves, each owns 4 tokens
#define RPW 28           // rows per wave (4 tokens x 7 nodes)
#define LN_EPS 1e-5f
#define ALPHA 0.2f
#define NEG_CONST -9e15f
#define SCALE 0.08838834764831845f  // 128^-0.5

typedef __bf16 bf16x8 __attribute__((ext_vector_type(8)));
typedef float  f32x4  __attribute__((ext_vector_type(4)));

// intra-wave LDS ordering; sched_barrier stops hoisting past the wait (rule #18)
#define FENCE() do { asm volatile("s_waitcnt lgkmcnt(0)" ::: "memory"); \
                     __builtin_amdgcn_sched_barrier(0); } while (0)

__device__ __forceinline__ uint16_t f2bf_u(float f) {
    union { float f; uint32_t u; } v; v.f = f;
    uint32_t r = v.u + 0x7FFFu + ((v.u >> 16) & 1u);  // RNE
    return (uint16_t)(r >> 16);
}
__device__ __forceinline__ uint32_t pack2(float a, float b) {
    return (uint32_t)f2bf_u(a) | ((uint32_t)f2bf_u(b) << 16);
}

// DPP lane-reduce: ctrl must be an ICE -> template parameter
template <int CTRL>
__device__ __forceinline__ float dpp_add(float v) {
    union { float f; int i; } a, r;
    a.f = v;
    r.i = __builtin_amdgcn_update_dpp(a.i, a.i, CTRL, 0xF, 0xF, false);
    return v + r.f;
}
__device__ __forceinline__ float sum16(float v) {
    v = dpp_add<0xB1>(v);    // quad_perm [1,0,3,2] : xor 1
    v = dpp_add<0x4E>(v);    // quad_perm [2,3,0,1] : xor 2
    v = dpp_add<0x124>(v);   // row_ror:4
    v = dpp_add<0x128>(v);   // row_ror:8
    return v;
}

// ws layout (bytes):
//  WpTp[896][32] bf16 @0 | W1Tp[128][128] bf16 @57344 | W2Tp[128][128] bf16 @90112
//  | vabp[2][2][128] f32 @122880 | bpp[896] f32 @124928 | gbp[2][2][128] f32 @128512
#define WS_W1T  57344
#define WS_W2T  90112
#define WS_VAB  122880
#define WS_BPP  124928
#define WS_GBP  128512

__global__ __launch_bounds__(256) void prep_weights(
    const float* __restrict__ Wp, const float* __restrict__ bp,
    const float* __restrict__ W1, const float* __restrict__ a1,
    const float* __restrict__ g1, const float* __restrict__ b1,
    const float* __restrict__ W2, const float* __restrict__ a2,
    const float* __restrict__ g2, const float* __restrict__ b2,
    uint16_t* __restrict__ WpT, uint16_t* __restrict__ W1T,
    uint16_t* __restrict__ W2T, float* __restrict__ vab,
    float* __restrict__ bpp, float* __restrict__ gbp)
{
    const int bid = blockIdx.x, tid = threadIdx.x;
    if (bid < 112) {                 // WpTp[sig(gc)][f] = Wp[f][gc]
        int idx = bid * 256 + tid;
        int gc = idx >> 5, f = idx & 31;
        int gcp = (gc & ~127) | (((gc & 15) << 3) | ((gc & 127) >> 4));
        WpT[gcp * 32 + f] = f2bf_u(Wp[(size_t)f * (NN * HD) + gc]);
    } else if (bid < 176) {          // W1Tp[c][sig(k)] = W1[k][c]
        int idx = (bid - 112) * 256 + tid;
        int c = idx >> 7, k = idx & 127;
        int kp = ((k & 15) << 3) | (k >> 4);
        W1T[c * 128 + kp] = f2bf_u(W1[(size_t)k * HD + c]);
    } else if (bid < 240) {          // W2Tp[c][sig(k)] = W2[k][c]
        int idx = (bid - 176) * 256 + tid;
        int c = idx >> 7, k = idx & 127;
        int kp = ((k & 15) << 3) | (k >> 4);
        W2T[c * 128 + kp] = f2bf_u(W2[(size_t)k * HD + c]);
    } else {
        // vabp[l][which][sig(j)] = sum_o W[j][o]*a[which*128+o]
        for (int d = tid; d < 512; d += 256) {
            int l = d >> 8, which = (d >> 7) & 1, j = d & 127;
            const float* W = l ? W2 : W1;
            const float* a = (l ? a2 : a1) + which * HD;
            const float* row = W + (size_t)j * HD;
            float acc = 0.f;
            #pragma unroll 8
            for (int o = 0; o < HD; o += 4) {
                f32x4 wv = *reinterpret_cast<const f32x4*>(&row[o]);
                acc += wv[0]*a[o] + wv[1]*a[o+1] + wv[2]*a[o+2] + wv[3]*a[o+3];
            }
            int jp = ((j & 15) << 3) | (j >> 4);
            vab[l * 256 + which * 128 + jp] = acc;
        }
        // bpp[sig_g(gc)] = bp[gc]
        for (int gc = tid; gc < NN * HD; gc += 256) {
            int gcp = (gc & ~127) | (((gc & 15) << 3) | ((gc & 127) >> 4));
            bpp[gcp] = bp[gc];
        }
        // gbp[l][{g,b}][sig(c)]
        for (int e = tid; e < 512; e += 256) {
            int l = e >> 8, which = (e >> 7) & 1, c = e & 127;
            const float* src = l ? (which ? b2 : g2) : (which ? b1 : g1);
            int cp = ((c & 15) << 3) | (c >> 4);
            gbp[l * 256 + which * 128 + cp] = src[c];
        }
    }
}

__global__ __launch_bounds__(256, 2) void gat_fused(
    const float* __restrict__ x, const float* __restrict__ adj,
    const float* __restrict__ bpp,
    const uint16_t* __restrict__ WpT, const uint16_t* __restrict__ W1T,
    const uint16_t* __restrict__ W2T, const float* __restrict__ vab,
    const float* __restrict__ gbp,
    float* __restrict__ out, int BT)
{
    // fp32 residual h, sigma-permuted cols; per-wave slice = 28 rows (4 tokens)
    __shared__ __align__(16) float h_s[4][RPW][132];   // 59136 B -> 2 blocks/CU

    const int tid  = threadIdx.x;
    const int lane = tid & 63;
    const int wave = tid >> 6;
    const int frow = lane & 15;
    const int kgrp = lane >> 4;
    const int kb   = kgrp * 8;
    const int t0   = blockIdx.x * TPB;

    // per-lane softmax-row identity: row0 = frow (clamped), row1 = 14+row0
    const int row0 = (frow > 13) ? 13 : frow;
    const int tb   = (row0 >= NN) ? 1 : 0;      // token-in-pair
    const int np   = row0 - tb * NN;            // node (same for both tiles)

    uint32_t amask = 0;
    #pragma unroll
    for (int j = 0; j < NN; ++j)
        amask |= (adj[np * NN + j] > 0.f) ? (1u << j) : 0u;

    // ---- B-frag: x for the block's 16 tokens (B col = token = frow) ----
    bf16x8 bx;
    {
        union { bf16x8 v; uint32_t u[4]; } bu;
        bu.u[0] = bu.u[1] = bu.u[2] = bu.u[3] = 0;
        int tok = t0 + frow;
        if (tok < BT) {
            f32x4 xa = *reinterpret_cast<const f32x4*>(&x[(size_t)tok * FIN + kb]);
            f32x4 xb = *reinterpret_cast<const f32x4*>(&x[(size_t)tok * FIN + kb + 4]);
            bu.u[0] = pack2(xa[0], xa[1]);
            bu.u[1] = pack2(xa[2], xa[3]);
            bu.u[2] = pack2(xb[0], xb[1]);
            bu.u[3] = pack2(xb[2], xb[3]);
        }
        bx = bu.v;
    }

    // ---- cooperative projection: 14 tiles/wave, all 16 B-cols used ----
    #pragma unroll 2
    for (int i = 0; i < 14; ++i) {
        int tile = wave * 14 + i;
        bf16x8 av = *reinterpret_cast<const bf16x8*>(WpT + (size_t)(tile * 16 + frow) * FIN + kb);
        f32x4 acc = {0.f, 0.f, 0.f, 0.f};
        acc = __builtin_amdgcn_mfma_f32_16x16x32_bf16(av, bx, acc, 0, 0, 0);
        int tok = t0 + frow;                 // C col = token, C row = out-col'
        if (tok < BT) {
            int gc0 = tile * 16 + kgrp * 4;  // 4 consecutive sigma-cols, same node
            f32x4 bias = *reinterpret_cast<const f32x4*>(&bpp[gc0]);
            f32x4 v = {acc[0]+bias[0], acc[1]+bias[1], acc[2]+bias[2], acc[3]+bias[3]};
            int n = gc0 >> 7, kk = gc0 & 127;
            // token frow -> wave slice frow>>2, local row (frow&3)*7+n
            *reinterpret_cast<f32x4*>(&h_s[frow >> 2][(frow & 3) * NN + n][kk]) = v;
        }
    }
    __syncthreads();   // the only block barrier

    for (int l = 0; l < 2; ++l) {
        const uint16_t* __restrict__ WT  = l ? W2T : W1T;
        const float*    __restrict__ vv0 = vab + l * 256;
        const float*    __restrict__ ggp = gbp + l * 256;  // [0..127]=gamma', [128..255]=beta'

        // ---- phase A: f-dots, full 128-dot per lane ----
        // lanes 0..27: f_src[row=lane]; lanes 32..59: f_dst[row=lane-32]
        float facc = 0.f;
        {
            int which = lane >> 5;
            int rr = lane & 31; if (rr > RPW - 1) rr = RPW - 1;
            const float* hr = &h_s[wave][rr][0];
            const f32x4* vp = reinterpret_cast<const f32x4*>(vv0 + which * HD);
            #pragma unroll
            for (int i2 = 0; i2 < 32; ++i2) {
                f32x4 hv = *reinterpret_cast<const f32x4*>(hr + i2 * 4);
                f32x4 w  = vp[i2];
                facc += hv[0]*w[0] + hv[1]*w[1] + hv[2]*w[2] + hv[3]*w[3];
            }
        }

        // ---- phase B: two softmax rows per lane (row0 tile0, row1 tile1) ----
        float p0[NN], p1[NN];
        {
            float fs0 = __shfl(facc, row0, 64);
            float fs1 = __shfl(facc, 14 + row0, 64);
            float e0[NN], e1[NN];
            float mx0 = -INFINITY, mx1 = -INFINITY;
            #pragma unroll
            for (int j = 0; j < NN; ++j) {
                float fd0 = __shfl(facc, 32 + tb * NN + j, 64);
                float fd1 = __shfl(facc, 32 + 14 + tb * NN + j, 64);
                float v0 = fs0 + fd0, v1 = fs1 + fd1;
                v0 = (v0 > 0.f ? v0 : ALPHA * v0) * SCALE;
                v1 = (v1 > 0.f ? v1 : ALPHA * v1) * SCALE;
                bool ok = (amask >> j) & 1u;
                v0 = ok ? v0 : NEG_CONST;
                v1 = ok ? v1 : NEG_CONST;
                e0[j] = v0; mx0 = fmaxf(mx0, v0);
                e1[j] = v1; mx1 = fmaxf(mx1, v1);
            }
            float s0 = 0.f, s1 = 0.f;
            #pragma unroll
            for (int j = 0; j < NN; ++j) {
                e0[j] = __expf(e0[j] - mx0); s0 += e0[j];
                e1[j] = __expf(e1[j] - mx1); s1 += e1[j];
            }
            float i0 = 1.f / s0, i1 = 1.f / s1;
            #pragma unroll
            for (int j = 0; j < NN; ++j) { p0[j] = e0[j] * i0; p1[j] = e1[j] * i1; }
        }

        // ---- phase C: A-frags for both tiles ----
        bf16x8 avA[4], avB[4];
        #pragma unroll
        for (int ks = 0; ks < 4; ++ks) {
            f32x4 ga0 = {0,0,0,0}, ga1 = {0,0,0,0};
            f32x4 gb0 = {0,0,0,0}, gb1 = {0,0,0,0};
            #pragma unroll
            for (int j = 0; j < NN; ++j) {
                const float* hj = &h_s[wave][tb * NN + j][ks * 32 + kb];
                f32x4 h0 = *reinterpret_cast<const f32x4*>(hj);
                f32x4 h1 = *reinterpret_cast<const f32x4*>(hj + 4);
                float pj = p0[j];
                ga0[0] += pj*h0[0]; ga0[1] += pj*h0[1]; ga0[2] += pj*h0[2]; ga0[3] += pj*h0[3];
                ga1[0] += pj*h1[0]; ga1[1] += pj*h1[1]; ga1[2] += pj*h1[2]; ga1[3] += pj*h1[3];
            }
            #pragma unroll
            for (int j = 0; j < NN; ++j) {
                const float* hj = &h_s[wave][14 + tb * NN + j][ks * 32 + kb];
                f32x4 h0 = *reinterpret_cast<const f32x4*>(hj);
                f32x4 h1 = *reinterpret_cast<const f32x4*>(hj + 4);
                float pj = p1[j];
                gb0[0] += pj*h0[0]; gb0[1] += pj*h0[1]; gb0[2] += pj*h0[2]; gb0[3] += pj*h0[3];
                gb1[0] += pj*h1[0]; gb1[1] += pj*h1[1]; gb1[2] += pj*h1[2]; gb1[3] += pj*h1[3];
            }
            union { bf16x8 v; uint32_t u[4]; } ba, bb;
            ba.u[0] = pack2(ga0[0], ga0[1]); ba.u[1] = pack2(ga0[2], ga0[3]);
            ba.u[2] = pack2(ga1[0], ga1[1]); ba.u[3] = pack2(ga1[2], ga1[3]);
            bb.u[0] = pack2(gb0[0], gb0[1]); bb.u[1] = pack2(gb0[2], gb0[3]);
            bb.u[2] = pack2(gb1[0], gb1[1]); bb.u[3] = pack2(gb1[2], gb1[3]);
            avA[ks] = ba.v; avB[ks] = bb.v;
        }

        // ---- phase D: two GEMM tiles share the B-frag loads (2x amortization) ----
        f32x4 C0[8], C1[8];
        #pragma unroll
        for (int ntl = 0; ntl < 8; ++ntl) {
            const uint16_t* bpg = WT + (size_t)(ntl * 16 + frow) * HD + kb;
            bf16x8 bv0 = *reinterpret_cast<const bf16x8*>(bpg);
            bf16x8 bv1 = *reinterpret_cast<const bf16x8*>(bpg + 32);
            bf16x8 bv2 = *reinterpret_cast<const bf16x8*>(bpg + 64);
            bf16x8 bv3 = *reinterpret_cast<const bf16x8*>(bpg + 96);
            f32x4 a0 = {0,0,0,0}, a1 = {0,0,0,0};
            a0 = __builtin_amdgcn_mfma_f32_16x16x32_bf16(avA[0], bv0, a0, 0, 0, 0);
            a1 = __builtin_amdgcn_mfma_f32_16x16x32_bf16(avB[0], bv0, a1, 0, 0, 0);
            a0 = __builtin_amdgcn_mfma_f32_16x16x32_bf16(avA[1], bv1, a0, 0, 0, 0);
            a1 = __builtin_amdgcn_mfma_f32_16x16x32_bf16(avB[1], bv1, a1, 0, 0, 0);
            a0 = __builtin_amdgcn_mfma_f32_16x16x32_bf16(avA[2], bv2, a0, 0, 0, 0);
            a1 = __builtin_amdgcn_mfma_f32_16x16x32_bf16(avB[2], bv2, a1, 0, 0, 0);
            a0 = __builtin_amdgcn_mfma_f32_16x16x32_bf16(avA[3], bv3, a0, 0, 0, 0);
            a1 = __builtin_amdgcn_mfma_f32_16x16x32_bf16(avB[3], bv3, a1, 0, 0, 0);
            C0[ntl] = a0; C1[ntl] = a1;
        }

        // ---- phase E: LayerNorm + residual for both tiles; b128 RMW ----
        {
            f32x4 gv0 = *reinterpret_cast<const f32x4*>(ggp + frow * 8);
            f32x4 gv1 = *reinterpret_cast<const f32x4*>(ggp + frow * 8 + 4);
            f32x4 bv0 = *reinterpret_cast<const f32x4*>(ggp + 128 + frow * 8);
            f32x4 bv1 = *reinterpret_cast<const f32x4*>(ggp + 128 + frow * 8 + 4);
            #pragma unroll
            for (int tile = 0; tile < 2; ++tile) {
                const f32x4* C = tile ? C1 : C0;
                const int mbase = tile * 14;
                #pragma unroll
                for (int r = 0; r < 4; ++r) {
                    float s = 0.f, sq = 0.f;
                    #pragma unroll
                    for (int q = 0; q < 8; ++q) { float c = C[q][r]; s += c; sq += c * c; }
                    s = sum16(s); sq = sum16(sq);   // DPP all-reduce over 16 frow-lanes
                    float mean = s * (1.f / HD);
                    float var  = sq * (1.f / HD) - mean * mean;
                    float rinv = rsqrtf(var + LN_EPS);
                    int m = kgrp * 4 + r;
                    if (m < 14) {
                        float* hp = &h_s[wave][mbase + m][frow * 8];
                        f32x4 h0 = *reinterpret_cast<const f32x4*>(hp);
                        f32x4 h1 = *reinterpret_cast<const f32x4*>(hp + 4);
                        h0[0] += (C[0][r]-mean)*rinv*gv0[0] + bv0[0];
                        h0[1] += (C[1][r]-mean)*rinv*gv0[1] + bv0[1];
                        h0[2] += (C[2][r]-mean)*rinv*gv0[2] + bv0[2];
                        h0[3] += (C[3][r]-mean)*rinv*gv0[3] + bv0[3];
                        h1[0] += (C[4][r]-mean)*rinv*gv1[0] + bv1[0];
                        h1[1] += (C[5][r]-mean)*rinv*gv1[1] + bv1[1];
                        h1[2] += (C[6][r]-mean)*rinv*gv1[2] + bv1[2];
                        h1[3] += (C[7][r]-mean)*rinv*gv1[3] + bv1[3];
                        *reinterpret_cast<f32x4*>(hp)     = h0;
                        *reinterpret_cast<f32x4*>(hp + 4) = h1;
                    }
                }
            }
        }
        FENCE();
    }

    // ---- out = mean over nodes; 4 tokens/wave; de-permute on store ----
    {
        int t_o = lane >> 4;            // 0..3
        int cq  = lane & 15;            // sigma col block cq*8..+7
        int tok = t0 + wave * 4 + t_o;
        if (tok < BT) {
            f32x4 s0 = {0,0,0,0}, s1 = {0,0,0,0};
            #pragma unroll
            for (int n = 0; n < NN; ++n) {
                const float* hp = &h_s[wave][t_o * NN + n][cq * 8];
                f32x4 h0 = *reinterpret_cast<const f32x4*>(hp);
                f32x4 h1 = *reinterpret_cast<const f32x4*>(hp + 4);
                s0[0]+=h0[0]; s0[1]+=h0[1]; s0[2]+=h0[2]; s0[3]+=h0[3];
                s1[0]+=h1[0]; s1[1]+=h1[1]; s1[2]+=h1[2]; s1[3]+=h1[3];
            }
            const float inv7 = 1.f / 7.f;
            float* ob = out + (size_t)tok * HD;
            // sigma col cp = cq*8+e  <->  orig col c = e*16+cq
            ob[0*16+cq] = s0[0]*inv7; ob[1*16+cq] = s0[1]*inv7;
            ob[2*16+cq] = s0[2]*inv7; ob[3*16+cq] = s0[3]*inv7;
            ob[4*16+cq] = s1[0]*inv7; ob[5*16+cq] = s1[1]*inv7;
            ob[6*16+cq] = s1[2]*inv7; ob[7*16+cq] = s1[3]*inv7;
        }
    }
}

extern "C" void kernel_launch(void* const* d_in, const int* in_sizes, int n_in,
                              void* d_out, int out_size, void* d_ws, size_t ws_size,
                              hipStream_t stream) {
    const float* x   = (const float*)d_in[0];
    const float* adj = (const float*)d_in[1];
    const float* Wp  = (const float*)d_in[2];
    const float* bp  = (const float*)d_in[3];
    const float* W1  = (const float*)d_in[4];
    const float* a1  = (const float*)d_in[5];
    const float* g1  = (const float*)d_in[6];
    const float* b1  = (const float*)d_in[7];
    const float* W2  = (const float*)d_in[8];
    const float* a2  = (const float*)d_in[9];
    const float* g2  = (const float*)d_in[10];
    const float* b2  = (const float*)d_in[11];
    const int BT = in_sizes[0] / FIN;
    const int blocks = (BT + TPB - 1) / TPB;

    uint8_t* ws = (uint8_t*)d_ws;
    uint16_t* WpT = (uint16_t*)(ws);
    uint16_t* W1T = (uint16_t*)(ws + WS_W1T);
    uint16_t* W2T = (uint16_t*)(ws + WS_W2T);
    float*    vab = (float*)   (ws + WS_VAB);
    float*    bpp = (float*)   (ws + WS_BPP);
    float*    gbp = (float*)   (ws + WS_GBP);

    prep_weights<<<dim3(241), dim3(256), 0, stream>>>(
        Wp, bp, W1, a1, g1, b1, W2, a2, g2, b2, WpT, W1T, W2T, vab, bpp, gbp);
    gat_fused<<<dim3(blocks), dim3(256), 0, stream>>>(
        x, adj, bpp, WpT, W1T, W2T, vab, gbp, (float*)d_out, BT);
}